// Round 11
// baseline (188.299 us; speedup 1.0000x reference)
//
#include <hip/hip_runtime.h>
#include <hip/hip_bf16.h>

#define N_NODES 50000
#define NE      800000
#define NT16    (NE / 16)
#define NTILES  (NE / 16)

typedef __attribute__((ext_vector_type(8)))  short bf16x8;
typedef __attribute__((ext_vector_type(4)))  float f32x4;
typedef __attribute__((ext_vector_type(16))) float f32x16;
typedef __attribute__((ext_vector_type(4)))  int   i32x4;
typedef __attribute__((ext_vector_type(2)))  int   i32x2;

static __device__ __forceinline__ short f2bf(float x) {
    union { float f; unsigned u; } v; v.f = x;
    unsigned r = (v.u + 0x7fffu + ((v.u >> 16) & 1u)) >> 16;  // RNE
    return (short)r;
}
static __device__ __forceinline__ float bflo(unsigned u) {
    union { unsigned u; float f; } v; v.u = u << 16; return v.f;
}
static __device__ __forceinline__ float bfhi(unsigned u) {
    union { unsigned u; float f; } v; v.u = u & 0xffff0000u; return v.f;
}
static __device__ __forceinline__ unsigned pk2bf(float a, float b) {
    union { __hip_bfloat162 h; unsigned u; } v;
    float2 f; f.x = a; f.y = b;
    v.h = __float22bfloat162_rn(f);
    return v.u;
}

// ---- GEMM image (for gemm_P): [W1cat frags 32768 B][bh 512 B] = 33280 B ----
#define GOFF_BH  32768
#define GIMG_B   33280
#define GIMG_V4  (GIMG_B / 16)   // 2080

// ---- edge image (for edge_mlp_p): [W2f 16384][b2c 128][gt1 512][gt2 256][w3 128] = 17408 B ----
#define I2_B2    16384
#define I2_GT1   16512
#define I2_GT2   17024
#define I2_W3    17280
#define IMG2_B   17408
#define IMG2_V4  (IMG2_B / 16)   // 1088

// ---- workspace layout ----
#define WS_P     0                      // 25,600,000 B  (P: [node][512B])
#define WS_GIMG  25600000
#define WS_IMG2  25633280
#define WS_OUTD  25650688
#define WS_IND   25850688
#define WS_NEED  26050688

// ---------------- prep: build images + degree hist ----------------
// W1cat[k][f] (k<64, f<256) = f<128 ? W1[k][f] : W1[64+k][f-128]
// GEMM A-frag (32x32x16): frag id = ft*4+ks; elem (lane=(h,c), j):
//   Wcat[16ks+8h+j][32ft+c]
// bh[f] = 0.5*b1[f&127]  (bias halves folded into P)
// W2f (16x16x32, R10-validated order): frag id = t2*4+ks; elem (lane=(g,c), j):
//   W2[(ks*32+g*8+j)*64 + t2*16 + c]
// gt1/gt2/w3: feature-linear packed (gamma|beta<<16), bf16.

__global__ void prep_all(const float* __restrict__ emb,
                         const int* __restrict__ src, const int* __restrict__ dst,
                         const float* __restrict__ W1, const float* __restrict__ b1,
                         const float* __restrict__ g1, const float* __restrict__ bt1,
                         const float* __restrict__ W2, const float* __restrict__ b2,
                         const float* __restrict__ g2, const float* __restrict__ bt2,
                         const float* __restrict__ W3,
                         char* __restrict__ gimg, char* __restrict__ img2,
                         int* __restrict__ outd, int* __restrict__ ind)
{
    const int i0 = blockIdx.x * 256 + threadIdx.x;
    const int n  = gridDim.x * 256;

    // degree hist (int4 loads)
    for (int t = i0; t < NE / 4; t += n) {
        i32x4 s4 = ((const i32x4*)src)[t];
        i32x4 d4 = ((const i32x4*)dst)[t];
        atomicAdd(outd + s4[0], 1); atomicAdd(outd + s4[1], 1);
        atomicAdd(outd + s4[2], 1); atomicAdd(outd + s4[3], 1);
        atomicAdd(ind + d4[0], 1); atomicAdd(ind + d4[1], 1);
        atomicAdd(ind + d4[2], 1); atomicAdd(ind + d4[3], 1);
    }
    // W1cat frags
    ushort* W1f = (ushort*)gimg;
    for (int t = i0; t < 16384; t += n) {
        int j = t & 7, lane = (t >> 3) & 63, f = t >> 9;   // f = ft*4+ks
        int ft = f >> 2, ks = f & 3, h = lane >> 5, cc = lane & 31;
        int k = 16 * ks + 8 * h + j;
        int fo = 32 * ft + cc;
        float v = (fo < 128) ? W1[k * 128 + fo] : W1[(64 + k) * 128 + (fo - 128)];
        W1f[t] = f2bf(v);
    }
    // bh
    if (i0 < 256) ((ushort*)(gimg + GOFF_BH))[i0] = f2bf(0.5f * b1[i0 & 127]);

    // W2f
    ushort* W2f = (ushort*)img2;
    for (int t = i0; t < 8192; t += n) {
        int j = t & 7, lane = (t >> 3) & 63, f = t >> 9;   // f = t2*4+ks
        int t2 = f >> 2, ks = f & 3, g = lane >> 4, c = lane & 15;
        W2f[t] = f2bf(W2[(ks * 32 + g * 8 + j) * 64 + t2 * 16 + c]);
    }
    if (i0 < 64)  ((ushort*)(img2 + I2_B2))[i0] = f2bf(b2[i0]);
    if (i0 < 128)
        ((unsigned*)(img2 + I2_GT1))[i0] =
            (unsigned)(ushort)f2bf(g1[i0]) | ((unsigned)(ushort)f2bf(bt1[i0]) << 16);
    if (i0 < 64) {
        ((unsigned*)(img2 + I2_GT2))[i0] =
            (unsigned)(ushort)f2bf(g2[i0]) | ((unsigned)(ushort)f2bf(bt2[i0]) << 16);
        ((ushort*)(img2 + I2_W3))[i0] = f2bf(W3[i0]);
    }
}

// ---------------- gemm_P: P[n] = [W1s^T emb[n] + b1/2 | W1d^T emb[n] + b1/2] ----------------
// 32x32x16 MFMA, features=M (256 over 8 ft tiles), nodes=N (32/tile).
// C: col=lane&31 (node), row=(reg&3)+8*(reg>>2)+4*(lane>>5) = f_local [m74/m101]
// P storage (per node, 512 B): ushort chunk layout so edge kernel lane (g,c)
// reads 64 B contiguous: addr = n*512 + half*256 + g*64 + t*8; chunk (g,t)
// holds bf16 features {16t+4g+r, r=0..3} of the half.

#define NT_NODE 1563   // ceil(50000/32)

__global__ __launch_bounds__(256, 2) void gemm_P(
    const float* __restrict__ emb, const i32x4* __restrict__ GIMG,
    ushort* __restrict__ P)
{
    __shared__ i32x4 ldsg[GIMG_V4];
    char* gb = (char*)ldsg;
    const int tid = threadIdx.x;
    for (int i = tid; i < GIMG_V4; i += 256) ldsg[i] = GIMG[i];
    __syncthreads();

    const int l = tid & 63;
    const int h = l >> 5;
    const int c = l & 31;

    bf16x8 bone = {};
    bone[0] = (h == 0) ? (short)0x3F80 : (short)0;

    const ushort* W1z = (const ushort*)gb;
    const ushort* bhz = (const ushort*)(gb + GOFF_BH);

    const int gw = blockIdx.x * 4 + (tid >> 6);
    const int nw = gridDim.x * 4;
    const int NTT = NT_NODE * 8;

    for (int tt = gw; tt < NTT; tt += nw) {
        const int nt = tt >> 3;          // node tile
        const int ft = tt & 7;           // feature tile
        const int nn = nt * 32 + c;
        const int ncl = (nn < N_NODES) ? nn : (N_NODES - 1);
        const float* er = emb + (size_t)ncl * 64;

        f32x16 acc = {};
#pragma unroll
        for (int ks = 0; ks < 4; ++ks) {
            f32x4 x0 = *(const f32x4*)(er + 16 * ks + 8 * h);
            f32x4 x1 = *(const f32x4*)(er + 16 * ks + 8 * h + 4);
            bf16x8 bf;
            bf[0] = f2bf(x0[0]); bf[1] = f2bf(x0[1]); bf[2] = f2bf(x0[2]); bf[3] = f2bf(x0[3]);
            bf[4] = f2bf(x1[0]); bf[5] = f2bf(x1[1]); bf[6] = f2bf(x1[2]); bf[7] = f2bf(x1[3]);
            bf16x8 w = *(const bf16x8*)(W1z + (ft * 4 + ks) * 512 + l * 8);
            acc = __builtin_amdgcn_mfma_f32_32x32x16_bf16(w, bf, acc, 0, 0, 0);
        }
        // bias (b1/2) fold
        {
            bf16x8 w = {};
            short bv = (short)bhz[32 * ft + c];
            w[0] = (h == 0) ? bv : (short)0;
            acc = __builtin_amdgcn_mfma_f32_32x32x16_bf16(w, bone, acc, 0, 0, 0);
        }
        if (nn < N_NODES) {
#pragma unroll
            for (int q = 0; q < 4; ++q) {
                int fl = 8 * q + 4 * h;          // f_local 0..31
                int f  = 32 * ft + fl;           // 0..255
                int fh = f & 127, half = f >> 7;
                int t  = fh >> 4, gg = (fh >> 2) & 3;
                ushort* dp = P + (size_t)nn * 256 + half * 128 + gg * 32 + t * 4;
                i32x2 o;
                o[0] = (int)pk2bf(acc[4 * q],     acc[4 * q + 1]);
                o[1] = (int)pk2bf(acc[4 * q + 2], acc[4 * q + 3]);
                *(i32x2*)dp = o;
            }
        }
    }
}

// ---------------- edge kernel: gather P halves, add, LN1, layer2 MFMA, LN2, gate ----------------
// 16 edges / wave-tile. Lane (g,c): edge c, feature set {16t+4g+r}.
// L2 B-frag exchange: per ks, target g needs pku[2ks+(g>>1)] words from lanes
// g'=2(g&1), 2(g&1)+1 -> 3 shuffles (xor16/32/48) + selects (derivation in notes).

__global__ __launch_bounds__(256, 4) void edge_mlp_p(
    const ushort* __restrict__ P,
    const int*   __restrict__ src, const int* __restrict__ dst,
    const float* __restrict__ noise,
    const i32x4* __restrict__ IMG2,
    const float* __restrict__ b3p,
    const int* __restrict__ outd, const int* __restrict__ ind,
    float* __restrict__ out)
{
    __shared__ i32x4 ldsv[IMG2_V4];
    char* ldsb = (char*)ldsv;

    const int tid = threadIdx.x;
    for (int i = tid; i < IMG2_V4; i += 256) ldsv[i] = IMG2[i];
    __syncthreads();

    const int l = tid & 63;
    const int g = l >> 4;
    const int c = l & 15;

    const float b3v = b3p[0];

    bf16x8 bone = {};
    bone[0] = (g == 0) ? (short)0x3F80 : (short)0;

    const int gw = blockIdx.x * 4 + (tid >> 6);
    const int nw = gridDim.x * 4;

    // ---- prologue: first tile indices + P gathers ----
    int sn, dn;
    i32x4 ps0, ps1, ps2, ps3, pd0, pd1, pd2, pd3;
    {
        int t0 = (gw < NT16) ? gw : (NT16 - 1);
        int e0p = t0 * 16 + c;
        sn = src[e0p]; dn = dst[e0p];
        const i32x4* sp = (const i32x4*)(P + (size_t)sn * 256 + g * 32);
        const i32x4* dp = (const i32x4*)(P + (size_t)dn * 256 + 128 + g * 32);
        ps0 = sp[0]; ps1 = sp[1]; ps2 = sp[2]; ps3 = sp[3];
        pd0 = dp[0]; pd1 = dp[1]; pd2 = dp[2]; pd3 = dp[3];
    }

    for (int tile = gw; tile < NT16; tile += nw) {
        unsigned tz;
        asm volatile("v_mov_b32 %0, 0" : "=v"(tz));   // anti-LICM anchor
        const char* ldz = ldsb + tz;

        const int e0 = tile * 16 + c;

        // next indices + epilogue operands
        const int tn  = tile + nw;
        const int tcl = (tn < NT16) ? tn : tile;
        const int e0n = tcl * 16 + c;
        int snN = src[e0n];
        int dnN = dst[e0n];
        float nz = noise[e0];
        int odv = outd[sn];
        int idv = ind[dn];

        // ---- LN1 stats from packed (h = bf(s)+bf(d), f32) ----
        float s = 0.f, q = 0.f;
        {
            i32x4 pcs[4] = {ps0, ps1, ps2, ps3};
            i32x4 pcd[4] = {pd0, pd1, pd2, pd3};
#pragma unroll
            for (int i = 0; i < 4; ++i) {
#pragma unroll
                for (int w = 0; w < 4; ++w) {
                    unsigned sv = (unsigned)pcs[i][w], dv = (unsigned)pcd[i][w];
                    float a = bflo(sv) + bflo(dv);
                    float b = bfhi(sv) + bfhi(dv);
                    s += a + b;
                    q = fmaf(a, a, fmaf(b, b, q));
                }
            }
        }
        s += __shfl_xor(s, 16); s += __shfl_xor(s, 32);
        q += __shfl_xor(q, 16); q += __shfl_xor(q, 32);
        const float mu = s * (1.0f / 128.0f);
        const float rs = rsqrtf(q * (1.0f / 128.0f) - mu * mu + 1e-5f);
        const float c0 = -mu * rs;

        // ---- LN1 apply + relu + pack pku[t][w] (recompute h from packed) ----
        unsigned pku[8][2];
        {
            i32x4 pcs[4] = {ps0, ps1, ps2, ps3};
            i32x4 pcd[4] = {pd0, pd1, pd2, pd3};
#pragma unroll
            for (int t = 0; t < 8; ++t) {
                i32x4 pg = *(const i32x4*)(ldz + I2_GT1 + t * 64 + g * 16);
                unsigned sv0 = (unsigned)pcs[t >> 1][(t & 1) * 2];
                unsigned sv1 = (unsigned)pcs[t >> 1][(t & 1) * 2 + 1];
                unsigned dv0 = (unsigned)pcd[t >> 1][(t & 1) * 2];
                unsigned dv1 = (unsigned)pcd[t >> 1][(t & 1) * 2 + 1];
                float h0 = bflo(sv0) + bflo(dv0);
                float h1_ = bfhi(sv0) + bfhi(dv0);
                float h2 = bflo(sv1) + bflo(dv1);
                float h3 = bfhi(sv1) + bfhi(dv1);
                float y0 = fmaxf(fmaf(fmaf(h0, rs, c0), bflo((unsigned)pg[0]), bfhi((unsigned)pg[0])), 0.f);
                float y1 = fmaxf(fmaf(fmaf(h1_, rs, c0), bflo((unsigned)pg[1]), bfhi((unsigned)pg[1])), 0.f);
                float y2 = fmaxf(fmaf(fmaf(h2, rs, c0), bflo((unsigned)pg[2]), bfhi((unsigned)pg[2])), 0.f);
                float y3 = fmaxf(fmaf(fmaf(h3, rs, c0), bflo((unsigned)pg[3]), bfhi((unsigned)pg[3])), 0.f);
                pku[t][0] = pk2bf(y0, y1);
                pku[t][1] = pk2bf(y2, y3);
            }
        }

        // ---- prefetch next-tile P gathers (ps/pd dead now) ----
        {
            const i32x4* sp = (const i32x4*)(P + (size_t)snN * 256 + g * 32);
            const i32x4* dp = (const i32x4*)(P + (size_t)dnN * 256 + 128 + g * 32);
            ps0 = sp[0]; ps1 = sp[1]; ps2 = sp[2]; ps3 = sp[3];
            pd0 = dp[0]; pd1 = dp[1]; pd2 = dp[2]; pd3 = dp[3];
        }

        // ---- layer 2: per ks build B-frag via xor16/32/48 exchange, 4 MFMAs ----
        const ushort* W2z = (const ushort*)ldz;
        f32x4 acc2[4] = {};
        const bool gh = (g & 2) != 0;
        const bool g0 = (g & 1) != 0;
#pragma unroll
        for (int ks = 0; ks < 4; ++ks) {
            unsigned o0 = pku[2 * ks][0],     o1 = pku[2 * ks][1];
            unsigned p0 = pku[2 * ks + 1][0], p1 = pku[2 * ks + 1][1];
            unsigned s16_0 = gh ? p0 : o0, s16_1 = gh ? p1 : o1;
            unsigned r16_0 = (unsigned)__shfl_xor((int)s16_0, 16);
            unsigned r16_1 = (unsigned)__shfl_xor((int)s16_1, 16);
            unsigned s32_0 = gh ? o0 : p0, s32_1 = gh ? o1 : p1;
            unsigned r32_0 = (unsigned)__shfl_xor((int)s32_0, 32);
            unsigned r32_1 = (unsigned)__shfl_xor((int)s32_1, 32);
            unsigned r48_0 = (unsigned)__shfl_xor((int)s32_0, 48);
            unsigned r48_1 = (unsigned)__shfl_xor((int)s32_1, 48);
            union { i32x4 i; bf16x8 b; } u;
            u.i[0] = (int)(g0 ? (gh ? r16_0 : r48_0) : (gh ? r32_0 : o0));
            u.i[1] = (int)(g0 ? (gh ? r16_1 : r48_1) : (gh ? r32_1 : o1));
            u.i[2] = (int)(g0 ? (gh ? p0 : r32_0) : (gh ? r48_0 : r16_0));
            u.i[3] = (int)(g0 ? (gh ? p1 : r32_1) : (gh ? r48_1 : r16_1));
#pragma unroll
            for (int t2 = 0; t2 < 4; ++t2) {
                bf16x8 w = *(const bf16x8*)(W2z + (t2 * 4 + ks) * 512 + l * 8);
                acc2[t2] = __builtin_amdgcn_mfma_f32_16x16x32_bf16(w, u.b, acc2[t2], 0, 0, 0);
            }
        }
        const ushort* b2z = (const ushort*)(ldz + I2_B2);
#pragma unroll
        for (int t2 = 0; t2 < 4; ++t2) {
            bf16x8 w = {};
            short bv = (short)b2z[t2 * 16 + c];
            w[0] = (g == 0) ? bv : (short)0;
            acc2[t2] = __builtin_amdgcn_mfma_f32_16x16x32_bf16(w, bone, acc2[t2], 0, 0, 0);
        }

        // ---- LN2 stats ----
        float t0 = 0.f, t1 = 0.f, p0s = 0.f, p1s = 0.f;
#pragma unroll
        for (int t2 = 0; t2 < 4; ++t2) {
            float v0 = acc2[t2][0], v1 = acc2[t2][1], v2 = acc2[t2][2], v3 = acc2[t2][3];
            t0 += v0 + v2; p0s = fmaf(v0, v0, fmaf(v2, v2, p0s));
            t1 += v1 + v3; p1s = fmaf(v1, v1, fmaf(v3, v3, p1s));
        }
        float s2 = t0 + t1, q2 = p0s + p1s;
        s2 += __shfl_xor(s2, 16); s2 += __shfl_xor(s2, 32);
        q2 += __shfl_xor(q2, 16); q2 += __shfl_xor(q2, 32);
        const float mu2 = s2 * (1.0f / 64.0f);
        const float rs2 = rsqrtf(q2 * (1.0f / 64.0f) - mu2 * mu2 + 1e-5f);
        const float c02 = -mu2 * rs2;

        // ---- LN2 apply + relu + dot(W3) ----
        float lg = 0.f;
#pragma unroll
        for (int t2 = 0; t2 < 4; ++t2) {
            i32x4 pg = *(const i32x4*)(ldz + I2_GT2 + t2 * 64 + g * 16);
            i32x2 wq = *(const i32x2*)(ldz + I2_W3 + t2 * 32 + g * 8);
#pragma unroll
            for (int r = 0; r < 4; ++r) {
                unsigned ug = (unsigned)pg[r];
                unsigned wu = (unsigned)wq[r >> 1];
                float w3v = (r & 1) ? bfhi(wu) : bflo(wu);
                float w = fmaf(acc2[t2][r], rs2, c02);
                float y = fmaxf(fmaf(w, bflo(ug), bfhi(ug)), 0.f);
                lg = fmaf(y, w3v, lg);
            }
        }
        lg += __shfl_xor(lg, 16);
        lg += __shfl_xor(lg, 32);
        lg += b3v;

        // ---- gate + degree norm (g==0 lanes: 16 edges) ----
        if (g == 0) {
            float z = __logf(nz) - log1pf(-nz) + lg;
            float gate = 1.0f / (1.0f + __expf(-z));
            int od = odv; if (od < 1) od = 1;
            int idg = idv; if (idg < 1) idg = 1;
            out[e0] = gate * (rsqrtf((float)od) * rsqrtf((float)idg));
        }

        sn = snN; dn = dnN;
    }
}

// ================= fallback (R2-validated) — used if ws too small =================

__global__ void degree_hist(const int* __restrict__ src, const int* __restrict__ dst,
                            int* __restrict__ outd, int* __restrict__ ind) {
    int i = blockIdx.x * 256 + threadIdx.x;
    if (i < NE) {
        atomicAdd(outd + src[i], 1);
        atomicAdd(ind + dst[i], 1);
    }
}

__global__ __launch_bounds__(256, 2) void edge_mlp_mfma(
    const float* __restrict__ emb,
    const int*   __restrict__ src, const int* __restrict__ dst,
    const float* __restrict__ noise,
    const float* __restrict__ W1, const float* __restrict__ b1,
    const float* __restrict__ g1, const float* __restrict__ bt1,
    const float* __restrict__ W2, const float* __restrict__ b2,
    const float* __restrict__ g2, const float* __restrict__ bt2,
    const float* __restrict__ W3, const float* __restrict__ b3,
    const int*   __restrict__ outd, const int* __restrict__ ind,
    float* __restrict__ out)
{
    __shared__ short lds[32768];
    const int tid = threadIdx.x;
    const int wid = tid >> 6;
    const int l   = tid & 63;
    const int g   = l >> 4;
    const int c   = l & 15;

    for (int i = tid; i < 16384; i += 256) {
        int j = i & 7, lane = (i >> 3) & 63, p = i >> 9;
        int ks = p >> 3, t = p & 7;
        int row = ks * 32 + (lane >> 4) * 8 + j;
        int col = t * 16 + (lane & 15);
        lds[i] = f2bf(W1[row * 128 + col]);
    }
    for (int i = tid; i < 8192; i += 256) {
        int j = i & 7, lane = (i >> 3) & 63, p = i >> 9;
        int ks = p >> 2, t = p & 3;
        int row = ks * 32 + (lane >> 4) * 8 + j;
        int col = t * 16 + (lane & 15);
        lds[16384 + i] = f2bf(W2[row * 64 + col]);
    }
    __syncthreads();

    short* Hl = lds + 24576 + wid * 2048;
    float b1v[8], g1v[8], t1v[8];
#pragma unroll
    for (int t = 0; t < 8; ++t) { int f = t * 16 + c; b1v[t] = b1[f]; g1v[t] = g1[f]; t1v[t] = bt1[f]; }
    float b2v[4], g2v[4], t2v[4], w3v[4];
#pragma unroll
    for (int t = 0; t < 4; ++t) { int f = t * 16 + c; b2v[t] = b2[f]; g2v[t] = g2[f]; t2v[t] = bt2[f]; w3v[t] = W3[f]; }
    const float b3v = b3[0];

    const int gw = blockIdx.x * 4 + wid;
    const int nw = gridDim.x * 4;

    for (int tile = gw; tile < NTILES; tile += nw) {
        const int e0 = tile * 16 + c;
        const int sn = src[e0], dn = dst[e0];
        const f32x4* sp = (const f32x4*)(emb + (size_t)sn * 64);
        const f32x4* dp = (const f32x4*)(emb + (size_t)dn * 64);
        f32x4 u[8];
        u[0] = sp[2 * g]; u[1] = sp[2 * g + 1];
        u[2] = sp[8 + 2 * g]; u[3] = sp[8 + 2 * g + 1];
        u[4] = dp[2 * g]; u[5] = dp[2 * g + 1];
        u[6] = dp[8 + 2 * g]; u[7] = dp[8 + 2 * g + 1];

        bf16x8 a1[4];
#pragma unroll
        for (int ks = 0; ks < 4; ++ks) {
            f32x4 x0 = u[2 * ks], x1 = u[2 * ks + 1];
            bf16x8 a;
            a[0] = f2bf(x0[0]); a[1] = f2bf(x0[1]); a[2] = f2bf(x0[2]); a[3] = f2bf(x0[3]);
            a[4] = f2bf(x1[0]); a[5] = f2bf(x1[1]); a[6] = f2bf(x1[2]); a[7] = f2bf(x1[3]);
            a1[ks] = a;
        }
        f32x4 acc1[8];
#pragma unroll
        for (int t = 0; t < 8; ++t) { f32x4 z = {b1v[t], b1v[t], b1v[t], b1v[t]}; acc1[t] = z; }
#pragma unroll
        for (int ks = 0; ks < 4; ++ks) {
#pragma unroll
            for (int t = 0; t < 8; ++t) {
                bf16x8 b = *(const bf16x8*)(lds + (ks * 8 + t) * 512 + l * 8);
                acc1[t] = __builtin_amdgcn_mfma_f32_16x16x32_bf16(a1[ks], b, acc1[t], 0, 0, 0);
            }
        }
        float mean[4], rstd[4];
#pragma unroll
        for (int r = 0; r < 4; ++r) {
            float s = acc1[0][r];
#pragma unroll
            for (int t = 1; t < 8; ++t) s += acc1[t][r];
            s += __shfl_xor(s, 1); s += __shfl_xor(s, 2);
            s += __shfl_xor(s, 4); s += __shfl_xor(s, 8);
            float m = s * (1.0f / 128.0f);
            float q = 0.f;
#pragma unroll
            for (int t = 0; t < 8; ++t) { float d = acc1[t][r] - m; q = fmaf(d, d, q); }
            q += __shfl_xor(q, 1); q += __shfl_xor(q, 2);
            q += __shfl_xor(q, 4); q += __shfl_xor(q, 8);
            mean[r] = m; rstd[r] = rsqrtf(q * (1.0f / 128.0f) + 1e-5f);
        }
#pragma unroll
        for (int r = 0; r < 4; ++r) {
            int rw = g * 4 + r;
            int swz = (rw & 7) << 3;
#pragma unroll
            for (int t = 0; t < 8; ++t) {
                float y = fmaf((acc1[t][r] - mean[r]) * rstd[r], g1v[t], t1v[t]);
                y = fmaxf(y, 0.f);
                Hl[rw * 128 + ((t * 16 + c) ^ swz)] = f2bf(y);
            }
        }
        bf16x8 a2[4];
        const int swzr = (c & 7) << 3;
#pragma unroll
        for (int ks = 0; ks < 4; ++ks)
            a2[ks] = *(const bf16x8*)(Hl + c * 128 + ((ks * 32 + g * 8) ^ swzr));

        f32x4 acc2[4];
#pragma unroll
        for (int t = 0; t < 4; ++t) { f32x4 z = {b2v[t], b2v[t], b2v[t], b2v[t]}; acc2[t] = z; }
#pragma unroll
        for (int ks = 0; ks < 4; ++ks) {
#pragma unroll
            for (int t = 0; t < 4; ++t) {
                bf16x8 b = *(const bf16x8*)(lds + 16384 + (ks * 4 + t) * 512 + l * 8);
                acc2[t] = __builtin_amdgcn_mfma_f32_16x16x32_bf16(a2[ks], b, acc2[t], 0, 0, 0);
            }
        }
        float logit[4];
#pragma unroll
        for (int r = 0; r < 4; ++r) {
            float s = acc2[0][r] + acc2[1][r] + acc2[2][r] + acc2[3][r];
            s += __shfl_xor(s, 1); s += __shfl_xor(s, 2);
            s += __shfl_xor(s, 4); s += __shfl_xor(s, 8);
            float m = s * (1.0f / 64.0f);
            float q = 0.f;
#pragma unroll
            for (int t = 0; t < 4; ++t) { float d = acc2[t][r] - m; q = fmaf(d, d, q); }
            q += __shfl_xor(q, 1); q += __shfl_xor(q, 2);
            q += __shfl_xor(q, 4); q += __shfl_xor(q, 8);
            float rs = rsqrtf(q * (1.0f / 64.0f) + 1e-5f);
            float p = 0.f;
#pragma unroll
            for (int t = 0; t < 4; ++t) {
                float y = fmaf((acc2[t][r] - m) * rs, g2v[t], t2v[t]);
                y = fmaxf(y, 0.f);
                p = fmaf(y, w3v[t], p);
            }
            p += __shfl_xor(p, 1); p += __shfl_xor(p, 2);
            p += __shfl_xor(p, 4); p += __shfl_xor(p, 8);
            logit[r] = p + b3v;
        }
        if (c < 4) {
            int e = tile * 16 + g * 4 + c;
            float lg = (c == 0) ? logit[0] : (c == 1) ? logit[1] : (c == 2) ? logit[2] : logit[3];
            float nz = noise[e];
            float z = __logf(nz) - log1pf(-nz) + lg;
            float gate = 1.0f / (1.0f + __expf(-z));
            int od = outd[src[e]]; if (od < 1) od = 1;
            int idg = ind[dst[e]]; if (idg < 1) idg = 1;
            out[e] = gate * (rsqrtf((float)od) * rsqrtf((float)idg));
        }
    }
}

// ---------------- launch ----------------

extern "C" void kernel_launch(void* const* d_in, const int* in_sizes, int n_in,
                              void* d_out, int out_size, void* d_ws, size_t ws_size,
                              hipStream_t stream) {
    const float* emb   = (const float*)d_in[0];
    const int*   src   = (const int*)  d_in[1];
    const int*   dst   = (const int*)  d_in[2];
    const float* noise = (const float*)d_in[3];
    const float* W1  = (const float*)d_in[4];
    const float* b1  = (const float*)d_in[5];
    const float* g1  = (const float*)d_in[6];
    const float* bt1 = (const float*)d_in[7];
    const float* W2  = (const float*)d_in[8];
    const float* b2  = (const float*)d_in[9];
    const float* g2  = (const float*)d_in[10];
    const float* bt2 = (const float*)d_in[11];
    const float* W3  = (const float*)d_in[12];
    const float* b3  = (const float*)d_in[13];

    char* ws = (char*)d_ws;

    if (ws_size >= (size_t)WS_NEED) {
        ushort* P    = (ushort*)(ws + WS_P);
        char*   gimg = ws + WS_GIMG;
        char*   img2 = ws + WS_IMG2;
        int* outd = (int*)(ws + WS_OUTD);
        int* ind  = (int*)(ws + WS_IND);

        hipMemsetAsync(outd, 0, 2 * N_NODES * sizeof(int), stream);
        prep_all<<<1024, 256, 0, stream>>>(emb, src, dst, W1, b1, g1, bt1,
                                           W2, b2, g2, bt2, W3,
                                           gimg, img2, outd, ind);
        gemm_P<<<1024, 256, 0, stream>>>(emb, (const i32x4*)gimg, P);
        edge_mlp_p<<<2048, 256, 0, stream>>>(P, src, dst, noise, (const i32x4*)img2,
                                             b3, outd, ind, (float*)d_out);
    } else {
        int* outd = (int*)ws;
        int* ind  = outd + N_NODES;
        hipMemsetAsync(outd, 0, 2 * N_NODES * sizeof(int), stream);
        degree_hist<<<(NE + 255) / 256, 256, 0, stream>>>(src, dst, outd, ind);
        edge_mlp_mfma<<<512, 256, 0, stream>>>(emb, src, dst, noise,
                                               W1, b1, g1, bt1,
                                               W2, b2, g2, bt2,
                                               W3, b3, outd, ind,
                                               (float*)d_out);
    }
}